// Round 2
// baseline (432.259 us; speedup 1.0000x reference)
//
#include <hip/hip_runtime.h>
#include <hip/hip_bf16.h>

// ViT attention, B=4 S=2048 C=1024 H=16 D=64. fp32 I/O, bf16 MFMA internally.
// Pipeline: cast(hs,w) -> qkv_gemm -> rope(Q,K) -> vtrans -> flash attn -> proj.

typedef unsigned short u16;
using bf16x8 = __attribute__((ext_vector_type(8))) __bf16;
using f32x4  = __attribute__((ext_vector_type(4))) float;

#define LDT 80  // LDS row stride (64 + 16 pad): keeps b128 16B-aligned

__device__ __forceinline__ u16 f2bf(float f) {
  union { float f; unsigned u; } un; un.f = f;
  unsigned r = un.u + 0x7FFFu + ((un.u >> 16) & 1u);  // RNE
  return (u16)(r >> 16);
}
__device__ __forceinline__ float bf2f(u16 b) {
  union { unsigned u; float f; } un; un.u = ((unsigned)b) << 16;
  return un.f;
}

// ---------------- fp32 -> bf16 cast (vectorized x4) ------------------------
__global__ __launch_bounds__(256) void f2bf_kernel(
    const float* __restrict__ src, u16* __restrict__ dst, int n4)
{
  int i = blockIdx.x * 256 + threadIdx.x;
  if (i < n4) {
    float4 v = ((const float4*)src)[i];
    ushort4 o;
    o.x = f2bf(v.x); o.y = f2bf(v.y); o.z = f2bf(v.z); o.w = f2bf(v.w);
    ((ushort4*)dst)[i] = o;
  }
}

// ---------------- 128x128 BT-GEMM core: out[m,n] = sum_k A[m,k]*B[n,k] -----
__device__ __forceinline__ void gemm_core_128(
    const u16* __restrict__ A, const u16* __restrict__ Bm, int K,
    int row0, int col0, u16* As, u16* Bs, f32x4 acc[4][4])
{
  const int tid = threadIdx.x;
  const int lane = tid & 63;
  const int w  = tid >> 6;            // wave 0..3
  const int wm = (w >> 1) << 6;       // wave row offset (0/64)
  const int wn = (w & 1) << 6;        // wave col offset (0/64)
  const int lr = lane & 15;           // A/B operand row within 16
  const int lk = (lane >> 4) << 3;    // k-offset within 32 (quad*8)
  const int sr = tid >> 3;            // staging row (0..31)
  const int sc = (tid & 7) << 3;      // staging col (x8 bf16)

  for (int k0 = 0; k0 < K; k0 += 64) {
    __syncthreads();
#pragma unroll
    for (int p = 0; p < 4; ++p) {
      int r = sr + p * 32;
      *(uint4*)(&As[r * LDT + sc]) = *(const uint4*)(A  + (size_t)(row0 + r) * K + k0 + sc);
      *(uint4*)(&Bs[r * LDT + sc]) = *(const uint4*)(Bm + (size_t)(col0 + r) * K + k0 + sc);
    }
    __syncthreads();
#pragma unroll
    for (int kk = 0; kk < 64; kk += 32) {
      bf16x8 af[4], bv[4];
#pragma unroll
      for (int i = 0; i < 4; ++i) {
        af[i] = *(const bf16x8*)(&As[(wm + i * 16 + lr) * LDT + kk + lk]);
        bv[i] = *(const bf16x8*)(&Bs[(wn + i * 16 + lr) * LDT + kk + lk]);
      }
#pragma unroll
      for (int i = 0; i < 4; ++i)
#pragma unroll
        for (int j = 0; j < 4; ++j)
          acc[i][j] = __builtin_amdgcn_mfma_f32_16x16x32_bf16(af[i], bv[j], acc[i][j], 0, 0, 0);
    }
  }
}

// ---------------- QKV projection + scatter to [B,H,S,D] --------------------
__global__ __launch_bounds__(256) void qkv_gemm_kernel(
    const u16* __restrict__ hs, const u16* __restrict__ wq,
    const float* __restrict__ bias,
    u16* __restrict__ Q, u16* __restrict__ K, u16* __restrict__ V)
{
  __shared__ u16 As[128 * LDT];
  __shared__ u16 Bs[128 * LDT];
  f32x4 acc[4][4];
#pragma unroll
  for (int i = 0; i < 4; ++i)
#pragma unroll
    for (int j = 0; j < 4; ++j) acc[i][j] = (f32x4){0.f, 0.f, 0.f, 0.f};

  const int row0 = blockIdx.y * 128;   // m = b*2048 + s
  const int col0 = blockIdx.x * 128;   // n in [0,3072)
  gemm_core_128(hs, wq, 1024, row0, col0, As, Bs, acc);

  const int lane = threadIdx.x & 63;
  const int w = threadIdx.x >> 6;
  const int wm = (w >> 1) << 6, wn = (w & 1) << 6;
#pragma unroll
  for (int i = 0; i < 4; ++i)
#pragma unroll
    for (int j = 0; j < 4; ++j)
#pragma unroll
      for (int r = 0; r < 4; ++r) {
        int m = row0 + wm + i * 16 + ((lane >> 4) << 2) + r;
        int n = col0 + wn + j * 16 + (lane & 15);
        float v = acc[i][j][r] + bias[n];
        int wh = n >> 10;        // 0=q 1=k 2=v
        int hd = n & 1023;       // h*64 + d
        int b = m >> 11, s = m & 2047;
        size_t off = ((size_t)((b << 4) + (hd >> 6)) * 2048 + s) * 64 + (hd & 63);
        u16* dst = (wh == 0) ? Q : ((wh == 1) ? K : V);
        dst[off] = f2bf(v);
      }
}

// ---------------- RoPE in-place on [B,H,S,D], cos/sin fp32 -----------------
__global__ __launch_bounds__(256) void rope_kernel(
    u16* __restrict__ X, const float* __restrict__ cs, const float* __restrict__ sn)
{
  int t = blockIdx.x * 256 + threadIdx.x;   // B*H*S*32 = 4194304 exact
  int d = t & 31;
  int bhs = t >> 5;                          // (b*16+h)*2048 + s
  int s = bhs & 2047;
  int b = bhs >> 15;
  size_t base = (size_t)bhs << 6;
  float q0 = bf2f(X[base + d]);
  float q1 = bf2f(X[base + d + 32]);
  size_t cb = ((size_t)(b * 2048 + s)) << 6;
  float c0 = cs[cb + d], c1 = cs[cb + d + 32];
  float s0 = sn[cb + d], s1 = sn[cb + d + 32];
  X[base + d]      = f2bf(q0 * c0 - q1 * s0);
  X[base + d + 32] = f2bf(q1 * c1 + q0 * s1);
}

// ---------------- V [B,H,S,D] -> Vt [B,H,D,S] ------------------------------
__global__ __launch_bounds__(256) void vtrans_kernel(
    const u16* __restrict__ V, u16* __restrict__ Vt)
{
  __shared__ u16 T[64][LDT];
  const int bh = blockIdx.y;
  const int s0 = blockIdx.x * 64;
  const u16* src = V + ((size_t)bh * 2048 + s0) * 64;
  const int r = threadIdx.x >> 2;
  const int c = (threadIdx.x & 3) << 4;
  *(uint4*)(&T[r][c])     = *(const uint4*)(src + r * 64 + c);
  *(uint4*)(&T[r][c + 8]) = *(const uint4*)(src + r * 64 + c + 8);
  __syncthreads();
  alignas(16) u16 tmp[16];
#pragma unroll
  for (int j = 0; j < 16; ++j) tmp[j] = T[c + j][r];
  u16* dst = Vt + ((size_t)bh * 64 + r) * 2048 + s0 + c;
  *(uint4*)(dst)     = *(uint4*)(&tmp[0]);
  *(uint4*)(dst + 8) = *(uint4*)(&tmp[8]);
}

// ---------------- flash attention, 64-row q tiles --------------------------
__global__ __launch_bounds__(256) void attn_kernel(
    const u16* __restrict__ Q, const u16* __restrict__ K,
    const u16* __restrict__ Vt, u16* __restrict__ O)
{
  __shared__ u16 Qs[64 * LDT];
  __shared__ u16 Ks[64 * LDT];
  __shared__ u16 Vs[64 * LDT];
  __shared__ u16 Ps[64 * LDT];
  const int bh = blockIdx.y;
  const int q0 = blockIdx.x << 6;
  const int b = bh >> 4, h = bh & 15;
  const u16* Qh = Q  + (size_t)bh * (2048 * 64);
  const u16* Kh = K  + (size_t)bh * (2048 * 64);
  const u16* Vh = Vt + (size_t)bh * (64 * 2048);
  const int tid = threadIdx.x, lane = tid & 63, w = tid >> 6;
  const int lr = lane & 15, lq = lane >> 4;
  const int sr = tid >> 3, sc = (tid & 7) << 3;

#pragma unroll
  for (int p = 0; p < 2; ++p) {
    int r = sr + p * 32;
    *(uint4*)(&Qs[r * LDT + sc]) = *(const uint4*)(Qh + (size_t)(q0 + r) * 64 + sc);
  }

  f32x4 acc_o[4];
#pragma unroll
  for (int td = 0; td < 4; ++td) acc_o[td] = (f32x4){0.f, 0.f, 0.f, 0.f};
  float mst[4], lst[4];
#pragma unroll
  for (int r = 0; r < 4; ++r) { mst[r] = -1e30f; lst[r] = 0.f; }

  for (int kv0 = 0; kv0 < 2048; kv0 += 64) {
    __syncthreads();
#pragma unroll
    for (int p = 0; p < 2; ++p) {
      int r = sr + p * 32;
      *(uint4*)(&Ks[r * LDT + sc]) = *(const uint4*)(Kh + (size_t)(kv0 + r) * 64 + sc);
      *(uint4*)(&Vs[r * LDT + sc]) = *(const uint4*)(Vh + (size_t)r * 2048 + kv0 + sc);
    }
    __syncthreads();

    // S = Q K^T : wave w owns q rows [w*16, w*16+16), all 64 kv cols
    f32x4 accs[4];
#pragma unroll
    for (int tj = 0; tj < 4; ++tj) accs[tj] = (f32x4){0.f, 0.f, 0.f, 0.f};
#pragma unroll
    for (int kk = 0; kk < 64; kk += 32) {
      bf16x8 a = *(const bf16x8*)(&Qs[(w * 16 + lr) * LDT + kk + lq * 8]);
#pragma unroll
      for (int tj = 0; tj < 4; ++tj) {
        bf16x8 bb = *(const bf16x8*)(&Ks[(tj * 16 + lr) * LDT + kk + lq * 8]);
        accs[tj] = __builtin_amdgcn_mfma_f32_16x16x32_bf16(a, bb, accs[tj], 0, 0, 0);
      }
    }

    // online softmax. C-layout: row = lq*4 + r (q), col = tj*16 + lr (kv)
    float pv[4][4], mx[4], alpha[4], rs[4];
#pragma unroll
    for (int tj = 0; tj < 4; ++tj)
#pragma unroll
      for (int r = 0; r < 4; ++r) pv[tj][r] = accs[tj][r] * 0.125f;
#pragma unroll
    for (int r = 0; r < 4; ++r)
      mx[r] = fmaxf(fmaxf(pv[0][r], pv[1][r]), fmaxf(pv[2][r], pv[3][r]));
#pragma unroll
    for (int mm = 1; mm < 16; mm <<= 1)
#pragma unroll
      for (int r = 0; r < 4; ++r) mx[r] = fmaxf(mx[r], __shfl_xor(mx[r], mm, 64));
#pragma unroll
    for (int r = 0; r < 4; ++r) {
      float mn = fmaxf(mst[r], mx[r]);
      alpha[r] = __expf(mst[r] - mn);
      mst[r] = mn;
    }
#pragma unroll
    for (int tj = 0; tj < 4; ++tj)
#pragma unroll
      for (int r = 0; r < 4; ++r) pv[tj][r] = __expf(pv[tj][r] - mst[r]);
#pragma unroll
    for (int r = 0; r < 4; ++r) rs[r] = pv[0][r] + pv[1][r] + pv[2][r] + pv[3][r];
#pragma unroll
    for (int mm = 1; mm < 16; mm <<= 1)
#pragma unroll
      for (int r = 0; r < 4; ++r) rs[r] += __shfl_xor(rs[r], mm, 64);
#pragma unroll
    for (int r = 0; r < 4; ++r) lst[r] = lst[r] * alpha[r] + rs[r];
#pragma unroll
    for (int td = 0; td < 4; ++td)
#pragma unroll
      for (int r = 0; r < 4; ++r) acc_o[td][r] *= alpha[r];

    // P: C-layout -> LDS -> A-layout
#pragma unroll
    for (int tj = 0; tj < 4; ++tj)
#pragma unroll
      for (int r = 0; r < 4; ++r)
        Ps[(w * 16 + lq * 4 + r) * LDT + tj * 16 + lr] = f2bf(pv[tj][r]);
    __syncthreads();

    // O += P V
#pragma unroll
    for (int kk = 0; kk < 64; kk += 32) {
      bf16x8 a = *(const bf16x8*)(&Ps[(w * 16 + lr) * LDT + kk + lq * 8]);
#pragma unroll
      for (int td = 0; td < 4; ++td) {
        bf16x8 bb = *(const bf16x8*)(&Vs[(td * 16 + lr) * LDT + kk + lq * 8]);
        acc_o[td] = __builtin_amdgcn_mfma_f32_16x16x32_bf16(a, bb, acc_o[td], 0, 0, 0);
      }
    }
  }

#pragma unroll
  for (int td = 0; td < 4; ++td)
#pragma unroll
    for (int r = 0; r < 4; ++r) {
      int qq = q0 + w * 16 + lq * 4 + r;
      int d = td * 16 + lr;
      float v = acc_o[td][r] / lst[r];
      O[(size_t)(b * 2048 + qq) * 1024 + h * 64 + d] = f2bf(v);
    }
}

// ---------------- output projection (fp32 out) -----------------------------
__global__ __launch_bounds__(256) void proj_gemm_kernel(
    const u16* __restrict__ X, const u16* __restrict__ wp,
    const float* __restrict__ bias, float* __restrict__ out)
{
  __shared__ u16 As[128 * LDT];
  __shared__ u16 Bs[128 * LDT];
  f32x4 acc[4][4];
#pragma unroll
  for (int i = 0; i < 4; ++i)
#pragma unroll
    for (int j = 0; j < 4; ++j) acc[i][j] = (f32x4){0.f, 0.f, 0.f, 0.f};

  const int row0 = blockIdx.y * 128;
  const int col0 = blockIdx.x * 128;
  gemm_core_128(X, wp, 1024, row0, col0, As, Bs, acc);

  const int lane = threadIdx.x & 63;
  const int w = threadIdx.x >> 6;
  const int wm = (w >> 1) << 6, wn = (w & 1) << 6;
#pragma unroll
  for (int i = 0; i < 4; ++i)
#pragma unroll
    for (int j = 0; j < 4; ++j)
#pragma unroll
      for (int r = 0; r < 4; ++r) {
        int m = row0 + wm + i * 16 + ((lane >> 4) << 2) + r;
        int n = col0 + wn + j * 16 + (lane & 15);
        out[(size_t)m * 1024 + n] = acc[i][j][r] + bias[n];
      }
}

extern "C" void kernel_launch(void* const* d_in, const int* in_sizes, int n_in,
                              void* d_out, int out_size, void* d_ws, size_t ws_size,
                              hipStream_t stream)
{
  const float* hs   = (const float*)d_in[0];  // hidden_states [4,2048,1024]
  const float* cs   = (const float*)d_in[1];  // cos [4,2048,64]
  const float* sn   = (const float*)d_in[2];  // sin [4,2048,64]
  const float* qkvw = (const float*)d_in[3];  // [3072,1024]
  const float* qkvb = (const float*)d_in[4];  // [3072]
  const float* pw   = (const float*)d_in[5];  // [1024,1024]
  const float* pb   = (const float*)d_in[6];  // [1024]
  float* out = (float*)d_out;                 // [4,2048,1024] fp32

  const size_t NQ = (size_t)8192 * 1024;      // B*H*S*D = 8388608
  u16* hsb   = (u16*)d_ws;                    // bf16 hidden_states
  u16* qkvwb = hsb + NQ;                      // bf16 qkv_w (3145728)
  u16* pwb   = qkvwb + 3145728;               // bf16 proj_w (1048576)
  u16* Qb    = pwb + 1048576;
  u16* Kb    = Qb + NQ;
  u16* Vb    = Kb + NQ;
  u16* Vtb   = Vb + NQ;
  u16* Ob    = hsb;                           // alias: hs consumed after qkv

  f2bf_kernel<<<8192, 256, 0, stream>>>(hs, hsb, (int)(NQ / 4));
  f2bf_kernel<<<3072, 256, 0, stream>>>(qkvw, qkvwb, 3145728 / 4);
  f2bf_kernel<<<1024, 256, 0, stream>>>(pw, pwb, 1048576 / 4);

  qkv_gemm_kernel<<<dim3(24, 64), 256, 0, stream>>>(hsb, qkvwb, qkvb, Qb, Kb, Vb);
  rope_kernel<<<16384, 256, 0, stream>>>(Qb, cs, sn);
  rope_kernel<<<16384, 256, 0, stream>>>(Kb, cs, sn);
  vtrans_kernel<<<dim3(32, 64), 256, 0, stream>>>(Vb, Vtb);
  attn_kernel<<<dim3(32, 64), 256, 0, stream>>>(Qb, Kb, Vtb, Ob);
  proj_gemm_kernel<<<dim3(8, 64), 256, 0, stream>>>(Ob, pwb, pb, out);
}

// Round 3
// 353.680 us; speedup vs baseline: 1.2222x; 1.2222x over previous
//
#include <hip/hip_runtime.h>
#include <hip/hip_bf16.h>

// ViT attention, B=4 S=2048 C=1024 H=16 D=64. fp32 I/O, bf16 MFMA internally.
// Pipeline: cast(hs,w) -> qkv_gemm(+bias+rope+1/8 scale) -> vtrans -> attn -> proj.

typedef unsigned short u16;
using bf16x8 = __attribute__((ext_vector_type(8))) __bf16;
using f32x4  = __attribute__((ext_vector_type(4))) float;

#define LDT 80  // GEMM LDS row stride (64 + 16 pad)
#define ALD 72  // attn LDS row stride: 144B = 4 banks/row shift, 4-row shift = 16 banks

__device__ __forceinline__ u16 f2bf(float f) {
  union { float f; unsigned u; } un; un.f = f;
  unsigned r = un.u + 0x7FFFu + ((un.u >> 16) & 1u);  // RNE
  return (u16)(r >> 16);
}
__device__ __forceinline__ float bf2f(u16 b) {
  union { unsigned u; float f; } un; un.u = ((unsigned)b) << 16;
  return un.f;
}

// ---------------- fp32 -> bf16 cast (vectorized x4) ------------------------
__global__ __launch_bounds__(256) void f2bf_kernel(
    const float* __restrict__ src, u16* __restrict__ dst, int n4)
{
  int i = blockIdx.x * 256 + threadIdx.x;
  if (i < n4) {
    float4 v = ((const float4*)src)[i];
    ushort4 o;
    o.x = f2bf(v.x); o.y = f2bf(v.y); o.z = f2bf(v.z); o.w = f2bf(v.w);
    ((ushort4*)dst)[i] = o;
  }
}

// ---------------- 128x128 BT-GEMM core: out[m,n] = sum_k A[m,k]*B[n,k] -----
__device__ __forceinline__ void gemm_core_128(
    const u16* __restrict__ A, const u16* __restrict__ Bm, int K,
    int row0, int col0, u16* As, u16* Bs, f32x4 acc[4][4])
{
  const int tid = threadIdx.x;
  const int lane = tid & 63;
  const int w  = tid >> 6;
  const int wm = (w >> 1) << 6;
  const int wn = (w & 1) << 6;
  const int lr = lane & 15;
  const int lk = (lane >> 4) << 3;
  const int sr = tid >> 3;
  const int sc = (tid & 7) << 3;

  for (int k0 = 0; k0 < K; k0 += 64) {
    __syncthreads();
#pragma unroll
    for (int p = 0; p < 4; ++p) {
      int r = sr + p * 32;
      *(uint4*)(&As[r * LDT + sc]) = *(const uint4*)(A  + (size_t)(row0 + r) * K + k0 + sc);
      *(uint4*)(&Bs[r * LDT + sc]) = *(const uint4*)(Bm + (size_t)(col0 + r) * K + k0 + sc);
    }
    __syncthreads();
#pragma unroll
    for (int kk = 0; kk < 64; kk += 32) {
      bf16x8 af[4], bv[4];
#pragma unroll
      for (int i = 0; i < 4; ++i) {
        af[i] = *(const bf16x8*)(&As[(wm + i * 16 + lr) * LDT + kk + lk]);
        bv[i] = *(const bf16x8*)(&Bs[(wn + i * 16 + lr) * LDT + kk + lk]);
      }
#pragma unroll
      for (int i = 0; i < 4; ++i)
#pragma unroll
        for (int j = 0; j < 4; ++j)
          acc[i][j] = __builtin_amdgcn_mfma_f32_16x16x32_bf16(af[i], bv[j], acc[i][j], 0, 0, 0);
    }
  }
}

// ------- QKV projection + bias + fused RoPE (+1/8 on Q) + scatter ----------
__global__ __launch_bounds__(256) void qkv_gemm_kernel(
    const u16* __restrict__ hs, const u16* __restrict__ wq,
    const float* __restrict__ bias,
    const float* __restrict__ cs, const float* __restrict__ sn,
    u16* __restrict__ Q, u16* __restrict__ K, u16* __restrict__ V)
{
  __shared__ __align__(16) u16 As[128 * LDT];
  __shared__ __align__(16) u16 Bs[128 * LDT];
  f32x4 acc[4][4];
#pragma unroll
  for (int i = 0; i < 4; ++i)
#pragma unroll
    for (int j = 0; j < 4; ++j) acc[i][j] = (f32x4){0.f, 0.f, 0.f, 0.f};

  const int row0 = blockIdx.y * 128;   // m = b*2048 + s
  const int col0 = blockIdx.x * 128;   // n in [0,3072)
  gemm_core_128(hs, wq, 1024, row0, col0, As, Bs, acc);

  const int lane = threadIdx.x & 63;
  const int w = threadIdx.x >> 6;
  const int lr = lane & 15, lq = lane >> 4;
  const int wm = (w >> 1) << 6, wn = (w & 1) << 6;
  const int ncol = col0 + wn;          // 64-aligned -> one (wh,h), d = 0..63
  const int wh = ncol >> 10;           // 0=q 1=k 2=v (wave-uniform)
  const int h  = (ncol & 1023) >> 6;
  u16* dst = (wh == 0) ? Q : ((wh == 1) ? K : V);
  const float b0 = bias[ncol + lr];
  const float b1 = bias[ncol + 16 + lr];
  const float b2 = bias[ncol + 32 + lr];
  const float b3 = bias[ncol + 48 + lr];

#pragma unroll
  for (int i = 0; i < 4; ++i)
#pragma unroll
    for (int r = 0; r < 4; ++r) {
      int m = row0 + wm + i * 16 + lq * 4 + r;   // = b*2048 + s
      float v0 = acc[i][0][r] + b0;
      float v1 = acc[i][1][r] + b1;
      float v2 = acc[i][2][r] + b2;
      float v3 = acc[i][3][r] + b3;
      if (wh < 2) {                    // RoPE on q,k
        size_t cb = (size_t)m << 6;
        float o0 = v0 * cs[cb + lr]      - v2 * sn[cb + lr];
        float o1 = v1 * cs[cb + 16 + lr] - v3 * sn[cb + 16 + lr];
        float o2 = v2 * cs[cb + 32 + lr] + v0 * sn[cb + 32 + lr];
        float o3 = v3 * cs[cb + 48 + lr] + v1 * sn[cb + 48 + lr];
        float sc8 = (wh == 0) ? 0.125f : 1.0f;   // fold 1/sqrt(D) into Q
        v0 = o0 * sc8; v1 = o1 * sc8; v2 = o2 * sc8; v3 = o3 * sc8;
      }
      int b = m >> 11, s = m & 2047;
      size_t off = ((size_t)((b << 4) + h) * 2048 + s) * 64;
      dst[off + lr]      = f2bf(v0);
      dst[off + 16 + lr] = f2bf(v1);
      dst[off + 32 + lr] = f2bf(v2);
      dst[off + 48 + lr] = f2bf(v3);
    }
}

// ---------------- V [B,H,S,D] -> Vt [B,H,D,S] ------------------------------
__global__ __launch_bounds__(256) void vtrans_kernel(
    const u16* __restrict__ V, u16* __restrict__ Vt)
{
  __shared__ __align__(16) u16 T[64][LDT];
  const int bh = blockIdx.y;
  const int s0 = blockIdx.x * 64;
  const u16* src = V + ((size_t)bh * 2048 + s0) * 64;
  const int r = threadIdx.x >> 2;
  const int c = (threadIdx.x & 3) << 4;
  *(uint4*)(&T[r][c])     = *(const uint4*)(src + r * 64 + c);
  *(uint4*)(&T[r][c + 8]) = *(const uint4*)(src + r * 64 + c + 8);
  __syncthreads();
  alignas(16) u16 tmp[16];
#pragma unroll
  for (int j = 0; j < 16; ++j) tmp[j] = T[c + j][r];
  u16* dst = Vt + ((size_t)bh * 64 + r) * 2048 + s0 + c;
  *(uint4*)(dst)     = *(uint4*)(&tmp[0]);
  *(uint4*)(dst + 8) = *(uint4*)(&tmp[8]);
}

// -------- flash attention: 128-row q tiles, no-max softmax, deferred sum ---
__global__ __launch_bounds__(256) void attn_kernel(
    const u16* __restrict__ Q, const u16* __restrict__ K,
    const u16* __restrict__ Vt, u16* __restrict__ O)
{
  __shared__ __align__(16) u16 Qs[128 * ALD];
  __shared__ __align__(16) u16 Ks[64 * ALD];
  __shared__ __align__(16) u16 Vs[64 * ALD];
  __shared__ __align__(16) u16 Ps[128 * ALD];
  const int bh = blockIdx.y;
  const int q0 = blockIdx.x << 7;
  const int b = bh >> 4, h = bh & 15;
  const u16* Qh = Q  + (size_t)bh * (2048 * 64);
  const u16* Kh = K  + (size_t)bh * (2048 * 64);
  const u16* Vh = Vt + (size_t)bh * (64 * 2048);
  const int tid = threadIdx.x, lane = tid & 63, w = tid >> 6;
  const int lr = lane & 15, lq = lane >> 4;
  const int sr = tid >> 3, sc = (tid & 7) << 3;
  const int wq0 = w * 32;              // wave's q-row base within tile

  // stage Q (128 rows), Q already pre-scaled by 1/8
#pragma unroll
  for (int p = 0; p < 4; ++p) {
    int r = sr + p * 32;
    *(uint4*)(&Qs[r * ALD + sc]) = *(const uint4*)(Qh + (size_t)(q0 + r) * 64 + sc);
  }

  f32x4 acc_o[2][4];
  float lsum[2][4];
#pragma unroll
  for (int mi = 0; mi < 2; ++mi)
#pragma unroll
    for (int td = 0; td < 4; ++td) acc_o[mi][td] = (f32x4){0.f, 0.f, 0.f, 0.f};
#pragma unroll
  for (int mi = 0; mi < 2; ++mi)
#pragma unroll
    for (int r = 0; r < 4; ++r) lsum[mi][r] = 0.f;

  for (int kv0 = 0; kv0 < 2048; kv0 += 64) {
    __syncthreads();   // prev iter's K/V reads done
#pragma unroll
    for (int p = 0; p < 2; ++p) {
      int r = sr + p * 32;
      *(uint4*)(&Ks[r * ALD + sc]) = *(const uint4*)(Kh + (size_t)(kv0 + r) * 64 + sc);
      *(uint4*)(&Vs[r * ALD + sc]) = *(const uint4*)(Vh + (size_t)r * 2048 + kv0 + sc);
    }
    __syncthreads();

    // S = Q K^T : wave owns 32 q rows x 64 kv cols
    f32x4 accs[2][4];
#pragma unroll
    for (int mi = 0; mi < 2; ++mi)
#pragma unroll
      for (int tj = 0; tj < 4; ++tj) accs[mi][tj] = (f32x4){0.f, 0.f, 0.f, 0.f};
#pragma unroll
    for (int kk = 0; kk < 64; kk += 32) {
      bf16x8 a[2];
#pragma unroll
      for (int mi = 0; mi < 2; ++mi)
        a[mi] = *(const bf16x8*)(&Qs[(wq0 + mi * 16 + lr) * ALD + kk + lq * 8]);
#pragma unroll
      for (int tj = 0; tj < 4; ++tj) {
        bf16x8 bb = *(const bf16x8*)(&Ks[(tj * 16 + lr) * ALD + kk + lq * 8]);
#pragma unroll
        for (int mi = 0; mi < 2; ++mi)
          accs[mi][tj] = __builtin_amdgcn_mfma_f32_16x16x32_bf16(a[mi], bb, accs[mi][tj], 0, 0, 0);
      }
    }

    // exp (no max subtraction; |s| <~ 15), accumulate per-lane partial sums
#pragma unroll
    for (int mi = 0; mi < 2; ++mi)
#pragma unroll
      for (int tj = 0; tj < 4; ++tj)
#pragma unroll
        for (int r = 0; r < 4; ++r) {
          float p = __expf(accs[mi][tj][r]);
          lsum[mi][r] += p;
          Ps[(wq0 + mi * 16 + lq * 4 + r) * ALD + tj * 16 + lr] = f2bf(p);
        }
    __syncthreads();

    // O += P V
#pragma unroll
    for (int kk = 0; kk < 64; kk += 32) {
      bf16x8 a[2];
#pragma unroll
      for (int mi = 0; mi < 2; ++mi)
        a[mi] = *(const bf16x8*)(&Ps[(wq0 + mi * 16 + lr) * ALD + kk + lq * 8]);
#pragma unroll
      for (int td = 0; td < 4; ++td) {
        bf16x8 bb = *(const bf16x8*)(&Vs[(td * 16 + lr) * ALD + kk + lq * 8]);
#pragma unroll
        for (int mi = 0; mi < 2; ++mi)
          acc_o[mi][td] = __builtin_amdgcn_mfma_f32_16x16x32_bf16(a[mi], bb, acc_o[mi][td], 0, 0, 0);
      }
    }
  }

  // single end-of-kernel row-sum reduction across the 16 lr lanes
#pragma unroll
  for (int mm = 1; mm < 16; mm <<= 1)
#pragma unroll
    for (int mi = 0; mi < 2; ++mi)
#pragma unroll
      for (int r = 0; r < 4; ++r)
        lsum[mi][r] += __shfl_xor(lsum[mi][r], mm, 64);

#pragma unroll
  for (int mi = 0; mi < 2; ++mi)
#pragma unroll
    for (int r = 0; r < 4; ++r) {
      float inv = 1.f / lsum[mi][r];
      int qq = q0 + wq0 + mi * 16 + lq * 4 + r;
#pragma unroll
      for (int td = 0; td < 4; ++td) {
        int d = td * 16 + lr;
        O[(size_t)(b * 2048 + qq) * 1024 + h * 64 + d] = f2bf(acc_o[mi][td][r] * inv);
      }
    }
}

// ---------------- output projection (fp32 out) -----------------------------
__global__ __launch_bounds__(256) void proj_gemm_kernel(
    const u16* __restrict__ X, const u16* __restrict__ wp,
    const float* __restrict__ bias, float* __restrict__ out)
{
  __shared__ __align__(16) u16 As[128 * LDT];
  __shared__ __align__(16) u16 Bs[128 * LDT];
  f32x4 acc[4][4];
#pragma unroll
  for (int i = 0; i < 4; ++i)
#pragma unroll
    for (int j = 0; j < 4; ++j) acc[i][j] = (f32x4){0.f, 0.f, 0.f, 0.f};

  const int row0 = blockIdx.y * 128;
  const int col0 = blockIdx.x * 128;
  gemm_core_128(X, wp, 1024, row0, col0, As, Bs, acc);

  const int lane = threadIdx.x & 63;
  const int w = threadIdx.x >> 6;
  const int wm = (w >> 1) << 6, wn = (w & 1) << 6;
#pragma unroll
  for (int i = 0; i < 4; ++i)
#pragma unroll
    for (int j = 0; j < 4; ++j)
#pragma unroll
      for (int r = 0; r < 4; ++r) {
        int m = row0 + wm + i * 16 + ((lane >> 4) << 2) + r;
        int n = col0 + wn + j * 16 + (lane & 15);
        out[(size_t)m * 1024 + n] = acc[i][j][r] + bias[n];
      }
}

extern "C" void kernel_launch(void* const* d_in, const int* in_sizes, int n_in,
                              void* d_out, int out_size, void* d_ws, size_t ws_size,
                              hipStream_t stream)
{
  const float* hs   = (const float*)d_in[0];
  const float* cs   = (const float*)d_in[1];
  const float* sn   = (const float*)d_in[2];
  const float* qkvw = (const float*)d_in[3];
  const float* qkvb = (const float*)d_in[4];
  const float* pw   = (const float*)d_in[5];
  const float* pb   = (const float*)d_in[6];
  float* out = (float*)d_out;

  const size_t NQ = (size_t)8192 * 1024;
  u16* hsb   = (u16*)d_ws;
  u16* qkvwb = hsb + NQ;
  u16* pwb   = qkvwb + 3145728;
  u16* Qb    = pwb + 1048576;
  u16* Kb    = Qb + NQ;
  u16* Vb    = Kb + NQ;
  u16* Vtb   = Vb + NQ;
  u16* Ob    = hsb;                    // alias: hs consumed after qkv

  f2bf_kernel<<<8192, 256, 0, stream>>>(hs, hsb, (int)(NQ / 4));
  f2bf_kernel<<<3072, 256, 0, stream>>>(qkvw, qkvwb, 3145728 / 4);
  f2bf_kernel<<<1024, 256, 0, stream>>>(pw, pwb, 1048576 / 4);

  qkv_gemm_kernel<<<dim3(24, 64), 256, 0, stream>>>(hsb, qkvwb, qkvb, cs, sn, Qb, Kb, Vb);
  vtrans_kernel<<<dim3(32, 64), 256, 0, stream>>>(Vb, Vtb);
  attn_kernel<<<dim3(16, 64), 256, 0, stream>>>(Qb, Kb, Vtb, Ob);
  proj_gemm_kernel<<<dim3(8, 64), 256, 0, stream>>>(Ob, pwb, pb, out);
}

// Round 5
// 313.323 us; speedup vs baseline: 1.3796x; 1.1288x over previous
//
#include <hip/hip_runtime.h>
#include <hip/hip_bf16.h>

// ViT attention, B=4 S=2048 C=1024 H=16 D=64. fp32 I/O, bf16/f16 MFMA inside.
// cast(hs,w) -> qkv_gemm(+bias+rope+scale, V->f16) -> vtrans -> attn -> proj.

typedef unsigned short u16;
using bf16x8 = __attribute__((ext_vector_type(8))) __bf16;
using f32x4  = __attribute__((ext_vector_type(4))) float;
using f16x4  = __attribute__((ext_vector_type(4))) _Float16;
using f16x2  = __attribute__((ext_vector_type(2))) _Float16;
using fp16v2 = __attribute__((ext_vector_type(2))) __fp16;   // cvt_pkrtz native

#define LDT 80  // vtrans LDS pad only

__device__ __forceinline__ u16 f2bf(float f) {
  union { float f; unsigned u; } un; un.f = f;
  unsigned r = un.u + 0x7FFFu + ((un.u >> 16) & 1u);  // RNE
  return (u16)(r >> 16);
}

// pack two f32 -> two f16 (RTZ) as _Float16 vector
__device__ __forceinline__ f16x2 pk16(float a, float b) {
  union { fp16v2 v; f16x2 f; } u;
  u.v = __builtin_amdgcn_cvt_pkrtz(a, b);
  return u.f;
}

// async 16B/lane global -> LDS (lands at ldsbase + lane*16)
__device__ __forceinline__ void glds16(const void* g, void* l) {
  __builtin_amdgcn_global_load_lds(
      (__attribute__((address_space(1))) void*)(g),
      (__attribute__((address_space(3))) void*)(l), 16, 0, 0);
}

// ---------------- fp32 -> bf16 cast (vectorized x4) ------------------------
__global__ __launch_bounds__(256) void f2bf_kernel(
    const float* __restrict__ src, u16* __restrict__ dst, int n4)
{
  int i = blockIdx.x * 256 + threadIdx.x;
  if (i < n4) {
    float4 v = ((const float4*)src)[i];
    ushort4 o;
    o.x = f2bf(v.x); o.y = f2bf(v.y); o.z = f2bf(v.z); o.w = f2bf(v.w);
    ((ushort4*)dst)[i] = o;
  }
}

// ------ 128x128 BT-GEMM core (m97-style global_load_lds staging) -----------
__device__ __forceinline__ void gemm_core_128(
    const u16* __restrict__ A, const u16* __restrict__ Bm, int K,
    int row0, int col0, u16* As, u16* Bs, f32x4 acc[4][4])
{
  const int tid = threadIdx.x;
  const int lane = tid & 63;
  const int w  = tid >> 6;
  const int wm = (w >> 1) << 6;
  const int wn = (w & 1) << 6;
  const int lr = lane & 15;
  const int lk = (lane >> 4) << 3;
  const int lrow = lane >> 3;         // 0..7 (row within 8-row group)
  const int lcol = (lane & 7) << 3;   // 0..56 (elem offset)

  for (int k0 = 0; k0 < K; k0 += 64) {
    __syncthreads();
#pragma unroll
    for (int p = 0; p < 4; ++p) {
      int base = w * 32 + p * 8;
      int rr = base + lrow;
      glds16(A  + (size_t)(row0 + rr) * K + k0 + lcol, &As[base * 64]);
      glds16(Bm + (size_t)(col0 + rr) * K + k0 + lcol, &Bs[base * 64]);
    }
    __syncthreads();
#pragma unroll
    for (int kk = 0; kk < 64; kk += 32) {
      bf16x8 af[4], bv[4];
#pragma unroll
      for (int i = 0; i < 4; ++i) {
        af[i] = *(const bf16x8*)(&As[(wm + i * 16 + lr) * 64 + kk + lk]);
        bv[i] = *(const bf16x8*)(&Bs[(wn + i * 16 + lr) * 64 + kk + lk]);
      }
#pragma unroll
      for (int i = 0; i < 4; ++i)
#pragma unroll
        for (int j = 0; j < 4; ++j)
          acc[i][j] = __builtin_amdgcn_mfma_f32_16x16x32_bf16(af[i], bv[j], acc[i][j], 0, 0, 0);
    }
  }
}

// ------- QKV projection + bias + fused RoPE + scale; V stored f16 ----------
__global__ __launch_bounds__(256) void qkv_gemm_kernel(
    const u16* __restrict__ hs, const u16* __restrict__ wq,
    const float* __restrict__ bias,
    const float* __restrict__ cs, const float* __restrict__ sn,
    u16* __restrict__ Q, u16* __restrict__ K, u16* __restrict__ V)
{
  __shared__ __align__(16) u16 As[128 * 64];
  __shared__ __align__(16) u16 Bs[128 * 64];
  f32x4 acc[4][4];
#pragma unroll
  for (int i = 0; i < 4; ++i)
#pragma unroll
    for (int j = 0; j < 4; ++j) acc[i][j] = (f32x4){0.f, 0.f, 0.f, 0.f};

  const int row0 = blockIdx.y * 128;   // m = b*2048 + s
  const int col0 = blockIdx.x * 128;   // n in [0,3072)
  gemm_core_128(hs, wq, 1024, row0, col0, As, Bs, acc);

  const int lane = threadIdx.x & 63;
  const int w = threadIdx.x >> 6;
  const int lr = lane & 15, lq = lane >> 4;
  const int wm = (w >> 1) << 6, wn = (w & 1) << 6;
  const int ncol = col0 + wn;          // 64-aligned -> single (wh,h)
  const int wh = ncol >> 10;           // 0=q 1=k 2=v (wave-uniform)
  const int h  = (ncol & 1023) >> 6;
  u16* dst = (wh == 0) ? Q : ((wh == 1) ? K : V);
  const float b0 = bias[ncol + lr];
  const float b1 = bias[ncol + 16 + lr];
  const float b2 = bias[ncol + 32 + lr];
  const float b3 = bias[ncol + 48 + lr];

#pragma unroll
  for (int i = 0; i < 4; ++i)
#pragma unroll
    for (int r = 0; r < 4; ++r) {
      int m = row0 + wm + i * 16 + lq * 4 + r;   // = b*2048 + s
      float v0 = acc[i][0][r] + b0;
      float v1 = acc[i][1][r] + b1;
      float v2 = acc[i][2][r] + b2;
      float v3 = acc[i][3][r] + b3;
      int b = m >> 11, s = m & 2047;
      size_t off = ((size_t)((b << 4) + h) * 2048 + s) * 64;
      if (wh == 2) {                   // V -> f16
        union { _Float16 h2; u16 u; } c0, c1, c2, c3;
        c0.h2 = (_Float16)v0; c1.h2 = (_Float16)v1;
        c2.h2 = (_Float16)v2; c3.h2 = (_Float16)v3;
        dst[off + lr]      = c0.u;
        dst[off + 16 + lr] = c1.u;
        dst[off + 32 + lr] = c2.u;
        dst[off + 48 + lr] = c3.u;
      } else {                         // RoPE on q,k; Q gets 1/8*log2(e)
        size_t cb = (size_t)m << 6;
        float o0 = v0 * cs[cb + lr]      - v2 * sn[cb + lr];
        float o1 = v1 * cs[cb + 16 + lr] - v3 * sn[cb + 16 + lr];
        float o2 = v2 * cs[cb + 32 + lr] + v0 * sn[cb + 32 + lr];
        float o3 = v3 * cs[cb + 48 + lr] + v1 * sn[cb + 48 + lr];
        float sc8 = (wh == 0) ? 0.1803368801f : 1.0f;
        dst[off + lr]      = f2bf(o0 * sc8);
        dst[off + 16 + lr] = f2bf(o1 * sc8);
        dst[off + 32 + lr] = f2bf(o2 * sc8);
        dst[off + 48 + lr] = f2bf(o3 * sc8);
      }
    }
}

// ---------------- V [B,H,S,D] -> Vt [B,H,D,S] (bit-moves) ------------------
__global__ __launch_bounds__(256) void vtrans_kernel(
    const u16* __restrict__ V, u16* __restrict__ Vt)
{
  __shared__ __align__(16) u16 T[64][LDT];
  const int bh = blockIdx.y;
  const int s0 = blockIdx.x * 64;
  const u16* src = V + ((size_t)bh * 2048 + s0) * 64;
  const int r = threadIdx.x >> 2;
  const int c = (threadIdx.x & 3) << 4;
  *(uint4*)(&T[r][c])     = *(const uint4*)(src + r * 64 + c);
  *(uint4*)(&T[r][c + 8]) = *(const uint4*)(src + r * 64 + c + 8);
  __syncthreads();
  alignas(16) u16 tmp[16];
#pragma unroll
  for (int j = 0; j < 16; ++j) tmp[j] = T[c + j][r];
  u16* dst = Vt + ((size_t)bh * 64 + r) * 2048 + s0 + c;
  *(uint4*)(dst)     = *(uint4*)(&tmp[0]);
  *(uint4*)(dst + 8) = *(uint4*)(&tmp[8]);
}

// ---- attention: S^T trick (C-layout == A-layout of 16x16x16), no P LDS ----
__global__ __launch_bounds__(256, 4) void attn_kernel(
    const u16* __restrict__ Q, const u16* __restrict__ K,
    const u16* __restrict__ Vt, u16* __restrict__ O)
{
  __shared__ __align__(16) u16 Ks[64 * 64];
  __shared__ __align__(16) u16 Vs[64 * 64];
  const int bh = blockIdx.y;
  const int q0 = blockIdx.x << 7;
  const int b = bh >> 4, h = bh & 15;
  const u16* Qh = Q  + (size_t)bh * (2048 * 64);
  const u16* Kh = K  + (size_t)bh * (2048 * 64);
  const u16* Vh = Vt + (size_t)bh * (64 * 2048);
  const int tid = threadIdx.x, lane = tid & 63, w = tid >> 6;
  const int lr = lane & 15, lq = lane >> 4;
  const int lrow = lane >> 3, lcol8 = lane & 7;
  const int wq0 = w * 32;

  // Q fragments: iter-invariant, straight from global (B-operand, n=q)
  bf16x8 qa[2][2];
#pragma unroll
  for (int mi = 0; mi < 2; ++mi)
#pragma unroll
    for (int kx = 0; kx < 2; ++kx)
      qa[mi][kx] = *(const bf16x8*)(Qh + (size_t)(q0 + wq0 + mi * 16 + lr) * 64 + kx * 32 + lq * 8);

  f32x4 acc_o[2][4];
  float lsum[2] = {0.f, 0.f};
#pragma unroll
  for (int mi = 0; mi < 2; ++mi)
#pragma unroll
    for (int td = 0; td < 4; ++td) acc_o[mi][td] = (f32x4){0.f, 0.f, 0.f, 0.f};

  for (int kv0 = 0; kv0 < 2048; kv0 += 64) {
    __syncthreads();
    // stage K,V with XOR-chunk swizzle (row r data chunk c lands at c^(r&7))
#pragma unroll
    for (int p = 0; p < 2; ++p) {
      int base = w * 16 + p * 8;
      int rr = base + lrow;
      int cc = (lcol8 ^ (rr & 7)) << 3;
      glds16(Kh + (size_t)(kv0 + rr) * 64 + cc, &Ks[base * 64]);
      glds16(Vh + (size_t)rr * 2048 + kv0 + cc, &Vs[base * 64]);
    }
    __syncthreads();

    // S^T = K Q^T : tiles [kv=tj*16][q=mi*16], contraction over d
    f32x4 st[4][2];
#pragma unroll
    for (int tj = 0; tj < 4; ++tj)
#pragma unroll
      for (int mi = 0; mi < 2; ++mi) st[tj][mi] = (f32x4){0.f, 0.f, 0.f, 0.f};
#pragma unroll
    for (int kx = 0; kx < 2; ++kx) {
      bf16x8 ka[4];
#pragma unroll
      for (int tj = 0; tj < 4; ++tj) {
        int row = tj * 16 + lr;
        ka[tj] = *(const bf16x8*)(&Ks[row * 64 + ((((kx << 2) + lq) ^ (lr & 7)) << 3)]);
      }
#pragma unroll
      for (int tj = 0; tj < 4; ++tj)
#pragma unroll
        for (int mi = 0; mi < 2; ++mi)
          st[tj][mi] = __builtin_amdgcn_mfma_f32_16x16x32_bf16(ka[tj], qa[mi][kx], st[tj][mi], 0, 0, 0);
    }

    // p = 2^s (log2e pre-folded into Q); pack straight into PV A-frags
    f16x4 pa[2][4];
#pragma unroll
    for (int mi = 0; mi < 2; ++mi)
#pragma unroll
      for (int tj = 0; tj < 4; ++tj) {
        float e0 = __builtin_amdgcn_exp2f(st[tj][mi][0]);
        float e1 = __builtin_amdgcn_exp2f(st[tj][mi][1]);
        float e2 = __builtin_amdgcn_exp2f(st[tj][mi][2]);
        float e3 = __builtin_amdgcn_exp2f(st[tj][mi][3]);
        lsum[mi] += (e0 + e1) + (e2 + e3);
        f16x2 lo = pk16(e0, e1);
        f16x2 hi = pk16(e2, e3);
        f16x4 p4;
        p4[0] = lo[0]; p4[1] = lo[1]; p4[2] = hi[0]; p4[3] = hi[1];
        pa[mi][tj] = p4;
      }

    // O += P V  (K=16 f16 MFMA; A-frag == S^T C-layout, identity)
#pragma unroll
    for (int t16 = 0; t16 < 4; ++t16) {
      f16x4 bv[4];
#pragma unroll
      for (int td = 0; td < 4; ++td) {
        int row = td * 16 + lr;
        int qc = (t16 << 1) + (lq >> 1);
        bv[td] = *(const f16x4*)(&Vs[row * 64 + ((qc ^ (lr & 7)) << 3) + ((lq & 1) << 2)]);
      }
#pragma unroll
      for (int td = 0; td < 4; ++td)
#pragma unroll
        for (int mi = 0; mi < 2; ++mi)
          acc_o[mi][td] = __builtin_amdgcn_mfma_f32_16x16x16f16(pa[mi][t16], bv[td], acc_o[mi][td], 0, 0, 0);
    }
  }

  // lsum lives at q=lr: reduce over the 4 quads, then fetch per-(lq,r) value
#pragma unroll
  for (int mi = 0; mi < 2; ++mi) {
    lsum[mi] += __shfl_xor(lsum[mi], 16, 64);
    lsum[mi] += __shfl_xor(lsum[mi], 32, 64);
  }
#pragma unroll
  for (int mi = 0; mi < 2; ++mi)
#pragma unroll
    for (int r = 0; r < 4; ++r) {
      float inv = 1.f / __shfl(lsum[mi], lq * 4 + r, 64);
      int qq = q0 + wq0 + mi * 16 + lq * 4 + r;
#pragma unroll
      for (int td = 0; td < 4; ++td) {
        int d = td * 16 + lr;
        O[(size_t)(b * 2048 + qq) * 1024 + h * 64 + d] = f2bf(acc_o[mi][td][r] * inv);
      }
    }
}

// ---------------- output projection (fp32 out) -----------------------------
__global__ __launch_bounds__(256) void proj_gemm_kernel(
    const u16* __restrict__ X, const u16* __restrict__ wp,
    const float* __restrict__ bias, float* __restrict__ out)
{
  __shared__ __align__(16) u16 As[128 * 64];
  __shared__ __align__(16) u16 Bs[128 * 64];
  f32x4 acc[4][4];
#pragma unroll
  for (int i = 0; i < 4; ++i)
#pragma unroll
    for (int j = 0; j < 4; ++j) acc[i][j] = (f32x4){0.f, 0.f, 0.f, 0.f};

  const int row0 = blockIdx.y * 128;
  const int col0 = blockIdx.x * 128;
  gemm_core_128(X, wp, 1024, row0, col0, As, Bs, acc);

  const int lane = threadIdx.x & 63;
  const int w = threadIdx.x >> 6;
  const int wm = (w >> 1) << 6, wn = (w & 1) << 6;
#pragma unroll
  for (int i = 0; i < 4; ++i)
#pragma unroll
    for (int j = 0; j < 4; ++j)
#pragma unroll
      for (int r = 0; r < 4; ++r) {
        int m = row0 + wm + i * 16 + ((lane >> 4) << 2) + r;
        int n = col0 + wn + j * 16 + (lane & 15);
        out[(size_t)m * 1024 + n] = acc[i][j][r] + bias[n];
      }
}

extern "C" void kernel_launch(void* const* d_in, const int* in_sizes, int n_in,
                              void* d_out, int out_size, void* d_ws, size_t ws_size,
                              hipStream_t stream)
{
  const float* hs   = (const float*)d_in[0];
  const float* cs   = (const float*)d_in[1];
  const float* sn   = (const float*)d_in[2];
  const float* qkvw = (const float*)d_in[3];
  const float* qkvb = (const float*)d_in[4];
  const float* pw   = (const float*)d_in[5];
  const float* pb   = (const float*)d_in[6];
  float* out = (float*)d_out;

  const size_t NQ = (size_t)8192 * 1024;
  u16* hsb   = (u16*)d_ws;
  u16* qkvwb = hsb + NQ;
  u16* pwb   = qkvwb + 3145728;
  u16* Qb    = pwb + 1048576;
  u16* Kb    = Qb + NQ;
  u16* Vb    = Kb + NQ;      // f16
  u16* Vtb   = Vb + NQ;      // f16
  u16* Ob    = hsb;          // alias: hs consumed after qkv

  f2bf_kernel<<<8192, 256, 0, stream>>>(hs, hsb, (int)(NQ / 4));
  f2bf_kernel<<<3072, 256, 0, stream>>>(qkvw, qkvwb, 3145728 / 4);
  f2bf_kernel<<<1024, 256, 0, stream>>>(pw, pwb, 1048576 / 4);

  qkv_gemm_kernel<<<dim3(24, 64), 256, 0, stream>>>(hsb, qkvwb, qkvb, cs, sn, Qb, Kb, Vb);
  vtrans_kernel<<<dim3(32, 64), 256, 0, stream>>>(Vb, Vtb);
  attn_kernel<<<dim3(16, 64), 256, 0, stream>>>(Qb, Kb, Vtb, Ob);
  proj_gemm_kernel<<<dim3(8, 64), 256, 0, stream>>>(Ob, pwb, pb, out);
}

// Round 6
// 309.417 us; speedup vs baseline: 1.3970x; 1.0126x over previous
//
#include <hip/hip_runtime.h>
#include <hip/hip_bf16.h>

// ViT attention, B=4 S=2048 C=1024 H=16 D=64. fp32 I/O, bf16/f16 MFMA inside.
// cast(hs,w) -> qkv_gemm(+bias+rope+scale, V->f16) -> vtrans -> attn -> proj.

typedef unsigned short u16;
using bf16x8 = __attribute__((ext_vector_type(8))) __bf16;
using f32x4  = __attribute__((ext_vector_type(4))) float;
using f16x4  = __attribute__((ext_vector_type(4))) _Float16;
using f16x2  = __attribute__((ext_vector_type(2))) _Float16;
using fp16v2 = __attribute__((ext_vector_type(2))) __fp16;   // cvt_pkrtz native

#define LDT 80  // vtrans LDS pad only

__device__ __forceinline__ u16 f2bf(float f) {
  union { float f; unsigned u; } un; un.f = f;
  unsigned r = un.u + 0x7FFFu + ((un.u >> 16) & 1u);  // RNE
  return (u16)(r >> 16);
}

// pack two f32 -> two f16 (RTZ) as _Float16 vector
__device__ __forceinline__ f16x2 pk16(float a, float b) {
  union { fp16v2 v; f16x2 f; } u;
  u.v = __builtin_amdgcn_cvt_pkrtz(a, b);
  return u.f;
}

// async 16B/lane global -> LDS (lands at ldsbase + lane*16)
__device__ __forceinline__ void glds16(const void* g, void* l) {
  __builtin_amdgcn_global_load_lds(
      (__attribute__((address_space(1))) void*)(g),
      (__attribute__((address_space(3))) void*)(l), 16, 0, 0);
}

// ---------------- fp32 -> bf16 cast (vectorized x4) ------------------------
__global__ __launch_bounds__(256) void f2bf_kernel(
    const float* __restrict__ src, u16* __restrict__ dst, int n4)
{
  int i = blockIdx.x * 256 + threadIdx.x;
  if (i < n4) {
    float4 v = ((const float4*)src)[i];
    ushort4 o;
    o.x = f2bf(v.x); o.y = f2bf(v.y); o.z = f2bf(v.z); o.w = f2bf(v.w);
    ((ushort4*)dst)[i] = o;
  }
}

// ------ 128x128 BT-GEMM core, glds staging + XOR bank swizzle --------------
// LDS row r chunk-slot s (16B chunks) holds global chunk s^(r&7); fragment
// reads address slot c^(r&7). 8 lr-groups cover all 32 banks (2-way = free).
__device__ __forceinline__ void gemm_core_128(
    const u16* __restrict__ A, const u16* __restrict__ Bm, int K,
    int row0, int col0, u16* As, u16* Bs, f32x4 acc[4][4])
{
  const int tid = threadIdx.x;
  const int lane = tid & 63;
  const int w  = tid >> 6;
  const int wm = (w >> 1) << 6;
  const int wn = (w & 1) << 6;
  const int lr = lane & 15;
  const int lq = lane >> 4;           // 0..3
  const int lrow = lane >> 3;         // 0..7 (row within 8-row group)
  const int lcol8 = lane & 7;         // chunk slot 0..7

  for (int k0 = 0; k0 < K; k0 += 64) {
    __syncthreads();
#pragma unroll
    for (int p = 0; p < 4; ++p) {
      int base = w * 32 + p * 8;
      int rr = base + lrow;
      int cc = (lcol8 ^ (rr & 7)) << 3;   // swizzled source chunk
      glds16(A  + (size_t)(row0 + rr) * K + k0 + cc, &As[base * 64]);
      glds16(Bm + (size_t)(col0 + rr) * K + k0 + cc, &Bs[base * 64]);
    }
    __syncthreads();
#pragma unroll
    for (int kx = 0; kx < 2; ++kx) {
      bf16x8 af[4], bv[4];
      const int sl = (((kx << 2) + lq) ^ (lr & 7)) << 3;
#pragma unroll
      for (int i = 0; i < 4; ++i) {
        af[i] = *(const bf16x8*)(&As[(wm + i * 16 + lr) * 64 + sl]);
        bv[i] = *(const bf16x8*)(&Bs[(wn + i * 16 + lr) * 64 + sl]);
      }
#pragma unroll
      for (int i = 0; i < 4; ++i)
#pragma unroll
        for (int j = 0; j < 4; ++j)
          acc[i][j] = __builtin_amdgcn_mfma_f32_16x16x32_bf16(af[i], bv[j], acc[i][j], 0, 0, 0);
    }
  }
}

// ------- QKV projection + bias + fused RoPE + scale; V stored f16 ----------
__global__ __launch_bounds__(256) void qkv_gemm_kernel(
    const u16* __restrict__ hs, const u16* __restrict__ wq,
    const float* __restrict__ bias,
    const float* __restrict__ cs, const float* __restrict__ sn,
    u16* __restrict__ Q, u16* __restrict__ K, u16* __restrict__ V)
{
  __shared__ __align__(16) u16 As[128 * 64];
  __shared__ __align__(16) u16 Bs[128 * 64];
  f32x4 acc[4][4];
#pragma unroll
  for (int i = 0; i < 4; ++i)
#pragma unroll
    for (int j = 0; j < 4; ++j) acc[i][j] = (f32x4){0.f, 0.f, 0.f, 0.f};

  const int row0 = blockIdx.y * 128;   // m = b*2048 + s
  const int col0 = blockIdx.x * 128;   // n in [0,3072)
  gemm_core_128(hs, wq, 1024, row0, col0, As, Bs, acc);

  const int lane = threadIdx.x & 63;
  const int w = threadIdx.x >> 6;
  const int lr = lane & 15, lq = lane >> 4;
  const int wm = (w >> 1) << 6, wn = (w & 1) << 6;
  const int ncol = col0 + wn;          // 64-aligned -> single (wh,h)
  const int wh = ncol >> 10;           // 0=q 1=k 2=v (wave-uniform)
  const int h  = (ncol & 1023) >> 6;
  u16* dst = (wh == 0) ? Q : ((wh == 1) ? K : V);
  const float b0 = bias[ncol + lr];
  const float b1 = bias[ncol + 16 + lr];
  const float b2 = bias[ncol + 32 + lr];
  const float b3 = bias[ncol + 48 + lr];

#pragma unroll
  for (int i = 0; i < 4; ++i)
#pragma unroll
    for (int r = 0; r < 4; ++r) {
      int m = row0 + wm + i * 16 + lq * 4 + r;   // = b*2048 + s
      float v0 = acc[i][0][r] + b0;
      float v1 = acc[i][1][r] + b1;
      float v2 = acc[i][2][r] + b2;
      float v3 = acc[i][3][r] + b3;
      int b = m >> 11, s = m & 2047;
      size_t off = ((size_t)((b << 4) + h) * 2048 + s) * 64;
      if (wh == 2) {                   // V -> f16
        union { _Float16 h2; u16 u; } c0, c1, c2, c3;
        c0.h2 = (_Float16)v0; c1.h2 = (_Float16)v1;
        c2.h2 = (_Float16)v2; c3.h2 = (_Float16)v3;
        dst[off + lr]      = c0.u;
        dst[off + 16 + lr] = c1.u;
        dst[off + 32 + lr] = c2.u;
        dst[off + 48 + lr] = c3.u;
      } else {                         // RoPE on q,k; Q gets 1/8*log2(e)
        size_t cb = (size_t)m << 6;
        float o0 = v0 * cs[cb + lr]      - v2 * sn[cb + lr];
        float o1 = v1 * cs[cb + 16 + lr] - v3 * sn[cb + 16 + lr];
        float o2 = v2 * cs[cb + 32 + lr] + v0 * sn[cb + 32 + lr];
        float o3 = v3 * cs[cb + 48 + lr] + v1 * sn[cb + 48 + lr];
        float sc8 = (wh == 0) ? 0.1803368801f : 1.0f;
        dst[off + lr]      = f2bf(o0 * sc8);
        dst[off + 16 + lr] = f2bf(o1 * sc8);
        dst[off + 32 + lr] = f2bf(o2 * sc8);
        dst[off + 48 + lr] = f2bf(o3 * sc8);
      }
    }
}

// ---------------- V [B,H,S,D] -> Vt [B,H,D,S] (bit-moves) ------------------
__global__ __launch_bounds__(256) void vtrans_kernel(
    const u16* __restrict__ V, u16* __restrict__ Vt)
{
  __shared__ __align__(16) u16 T[64][LDT];
  const int bh = blockIdx.y;
  const int s0 = blockIdx.x * 64;
  const u16* src = V + ((size_t)bh * 2048 + s0) * 64;
  const int r = threadIdx.x >> 2;
  const int c = (threadIdx.x & 3) << 4;
  *(uint4*)(&T[r][c])     = *(const uint4*)(src + r * 64 + c);
  *(uint4*)(&T[r][c + 8]) = *(const uint4*)(src + r * 64 + c + 8);
  __syncthreads();
  alignas(16) u16 tmp[16];
#pragma unroll
  for (int j = 0; j < 16; ++j) tmp[j] = T[c + j][r];
  u16* dst = Vt + ((size_t)bh * 64 + r) * 2048 + s0 + c;
  *(uint4*)(dst)     = *(uint4*)(&tmp[0]);
  *(uint4*)(dst + 8) = *(uint4*)(&tmp[8]);
}

// ---- attention: S^T trick (C-layout == A-layout of 16x16x16), no P LDS ----
__global__ __launch_bounds__(256, 4) void attn_kernel(
    const u16* __restrict__ Q, const u16* __restrict__ K,
    const u16* __restrict__ Vt, u16* __restrict__ O)
{
  __shared__ __align__(16) u16 Ks[64 * 64];
  __shared__ __align__(16) u16 Vs[64 * 64];
  const int bh = blockIdx.y;
  const int q0 = blockIdx.x << 7;
  const int b = bh >> 4, h = bh & 15;
  const u16* Qh = Q  + (size_t)bh * (2048 * 64);
  const u16* Kh = K  + (size_t)bh * (2048 * 64);
  const u16* Vh = Vt + (size_t)bh * (64 * 2048);
  const int tid = threadIdx.x, lane = tid & 63, w = tid >> 6;
  const int lr = lane & 15, lq = lane >> 4;
  const int lrow = lane >> 3, lcol8 = lane & 7;
  const int wq0 = w * 32;

  // Q fragments: iter-invariant, straight from global (B-operand, n=q)
  bf16x8 qa[2][2];
#pragma unroll
  for (int mi = 0; mi < 2; ++mi)
#pragma unroll
    for (int kx = 0; kx < 2; ++kx)
      qa[mi][kx] = *(const bf16x8*)(Qh + (size_t)(q0 + wq0 + mi * 16 + lr) * 64 + kx * 32 + lq * 8);

  f32x4 acc_o[2][4];
  float lsum[2] = {0.f, 0.f};
#pragma unroll
  for (int mi = 0; mi < 2; ++mi)
#pragma unroll
    for (int td = 0; td < 4; ++td) acc_o[mi][td] = (f32x4){0.f, 0.f, 0.f, 0.f};

  for (int kv0 = 0; kv0 < 2048; kv0 += 64) {
    __syncthreads();
    // stage K,V with XOR-chunk swizzle (row r data chunk c lands at c^(r&7))
#pragma unroll
    for (int p = 0; p < 2; ++p) {
      int base = w * 16 + p * 8;
      int rr = base + lrow;
      int cc = (lcol8 ^ (rr & 7)) << 3;
      glds16(Kh + (size_t)(kv0 + rr) * 64 + cc, &Ks[base * 64]);
      glds16(Vh + (size_t)rr * 2048 + kv0 + cc, &Vs[base * 64]);
    }
    __syncthreads();

    // S^T = K Q^T : tiles [kv=tj*16][q=mi*16], contraction over d
    f32x4 st[4][2];
#pragma unroll
    for (int tj = 0; tj < 4; ++tj)
#pragma unroll
      for (int mi = 0; mi < 2; ++mi) st[tj][mi] = (f32x4){0.f, 0.f, 0.f, 0.f};
#pragma unroll
    for (int kx = 0; kx < 2; ++kx) {
      bf16x8 ka[4];
#pragma unroll
      for (int tj = 0; tj < 4; ++tj) {
        int row = tj * 16 + lr;
        ka[tj] = *(const bf16x8*)(&Ks[row * 64 + ((((kx << 2) + lq) ^ (lr & 7)) << 3)]);
      }
#pragma unroll
      for (int tj = 0; tj < 4; ++tj)
#pragma unroll
        for (int mi = 0; mi < 2; ++mi)
          st[tj][mi] = __builtin_amdgcn_mfma_f32_16x16x32_bf16(ka[tj], qa[mi][kx], st[tj][mi], 0, 0, 0);
    }

    // p = 2^s (log2e pre-folded into Q); pack straight into PV A-frags
    f16x4 pa[2][4];
#pragma unroll
    for (int mi = 0; mi < 2; ++mi)
#pragma unroll
      for (int tj = 0; tj < 4; ++tj) {
        float e0 = __builtin_amdgcn_exp2f(st[tj][mi][0]);
        float e1 = __builtin_amdgcn_exp2f(st[tj][mi][1]);
        float e2 = __builtin_amdgcn_exp2f(st[tj][mi][2]);
        float e3 = __builtin_amdgcn_exp2f(st[tj][mi][3]);
        lsum[mi] += (e0 + e1) + (e2 + e3);
        f16x2 lo = pk16(e0, e1);
        f16x2 hi = pk16(e2, e3);
        f16x4 p4;
        p4[0] = lo[0]; p4[1] = lo[1]; p4[2] = hi[0]; p4[3] = hi[1];
        pa[mi][tj] = p4;
      }

    // O += P V  (K=16 f16 MFMA; A-frag == S^T C-layout, identity)
#pragma unroll
    for (int t16 = 0; t16 < 4; ++t16) {
      f16x4 bv[4];
#pragma unroll
      for (int td = 0; td < 4; ++td) {
        int row = td * 16 + lr;
        int qc = (t16 << 1) + (lq >> 1);
        bv[td] = *(const f16x4*)(&Vs[row * 64 + ((qc ^ (lr & 7)) << 3) + ((lq & 1) << 2)]);
      }
#pragma unroll
      for (int td = 0; td < 4; ++td)
#pragma unroll
        for (int mi = 0; mi < 2; ++mi)
          acc_o[mi][td] = __builtin_amdgcn_mfma_f32_16x16x16f16(pa[mi][t16], bv[td], acc_o[mi][td], 0, 0, 0);
    }
  }

  // lsum lives at q=lr: reduce over the 4 quads, then fetch per-(lq,r) value
#pragma unroll
  for (int mi = 0; mi < 2; ++mi) {
    lsum[mi] += __shfl_xor(lsum[mi], 16, 64);
    lsum[mi] += __shfl_xor(lsum[mi], 32, 64);
  }
#pragma unroll
  for (int mi = 0; mi < 2; ++mi)
#pragma unroll
    for (int r = 0; r < 4; ++r) {
      float inv = 1.f / __shfl(lsum[mi], lq * 4 + r, 64);
      int qq = q0 + wq0 + mi * 16 + lq * 4 + r;
#pragma unroll
      for (int td = 0; td < 4; ++td) {
        int d = td * 16 + lr;
        O[(size_t)(b * 2048 + qq) * 1024 + h * 64 + d] = f2bf(acc_o[mi][td][r] * inv);
      }
    }
}

// ---------------- output projection (fp32 out) -----------------------------
__global__ __launch_bounds__(256) void proj_gemm_kernel(
    const u16* __restrict__ X, const u16* __restrict__ wp,
    const float* __restrict__ bias, float* __restrict__ out)
{
  __shared__ __align__(16) u16 As[128 * 64];
  __shared__ __align__(16) u16 Bs[128 * 64];
  f32x4 acc[4][4];
#pragma unroll
  for (int i = 0; i < 4; ++i)
#pragma unroll
    for (int j = 0; j < 4; ++j) acc[i][j] = (f32x4){0.f, 0.f, 0.f, 0.f};

  const int row0 = blockIdx.y * 128;
  const int col0 = blockIdx.x * 128;
  gemm_core_128(X, wp, 1024, row0, col0, As, Bs, acc);

  const int lane = threadIdx.x & 63;
  const int w = threadIdx.x >> 6;
  const int wm = (w >> 1) << 6, wn = (w & 1) << 6;
#pragma unroll
  for (int i = 0; i < 4; ++i)
#pragma unroll
    for (int j = 0; j < 4; ++j)
#pragma unroll
      for (int r = 0; r < 4; ++r) {
        int m = row0 + wm + i * 16 + ((lane >> 4) << 2) + r;
        int n = col0 + wn + j * 16 + (lane & 15);
        out[(size_t)m * 1024 + n] = acc[i][j][r] + bias[n];
      }
}

extern "C" void kernel_launch(void* const* d_in, const int* in_sizes, int n_in,
                              void* d_out, int out_size, void* d_ws, size_t ws_size,
                              hipStream_t stream)
{
  const float* hs   = (const float*)d_in[0];
  const float* cs   = (const float*)d_in[1];
  const float* sn   = (const float*)d_in[2];
  const float* qkvw = (const float*)d_in[3];
  const float* qkvb = (const float*)d_in[4];
  const float* pw   = (const float*)d_in[5];
  const float* pb   = (const float*)d_in[6];
  float* out = (float*)d_out;

  const size_t NQ = (size_t)8192 * 1024;
  u16* hsb   = (u16*)d_ws;
  u16* qkvwb = hsb + NQ;
  u16* pwb   = qkvwb + 3145728;
  u16* Qb    = pwb + 1048576;
  u16* Kb    = Qb + NQ;
  u16* Vb    = Kb + NQ;      // f16
  u16* Vtb   = Vb + NQ;      // f16
  u16* Ob    = hsb;          // alias: hs consumed after qkv

  f2bf_kernel<<<8192, 256, 0, stream>>>(hs, hsb, (int)(NQ / 4));
  f2bf_kernel<<<3072, 256, 0, stream>>>(qkvw, qkvwb, 3145728 / 4);
  f2bf_kernel<<<1024, 256, 0, stream>>>(pw, pwb, 1048576 / 4);

  qkv_gemm_kernel<<<dim3(24, 64), 256, 0, stream>>>(hsb, qkvwb, qkvb, cs, sn, Qb, Kb, Vb);
  vtrans_kernel<<<dim3(32, 64), 256, 0, stream>>>(Vb, Vtb);
  attn_kernel<<<dim3(16, 64), 256, 0, stream>>>(Qb, Kb, Vtb, Ob);
  proj_gemm_kernel<<<dim3(8, 64), 256, 0, stream>>>(Ob, pwb, pb, out);
}

// Round 7
// 304.717 us; speedup vs baseline: 1.4186x; 1.0154x over previous
//
#include <hip/hip_runtime.h>
#include <hip/hip_bf16.h>

// ViT attention, B=4 S=2048 C=1024 H=16 D=64. fp32 I/O, bf16/f16 MFMA inside.
// cast -> rope_table -> qkv_gemm(+bias+rope+scale) -> vtrans -> attn -> proj.

typedef unsigned short u16;
using bf16x8 = __attribute__((ext_vector_type(8))) __bf16;
using f32x4  = __attribute__((ext_vector_type(4))) float;
using f16x4  = __attribute__((ext_vector_type(4))) _Float16;
using f16x2  = __attribute__((ext_vector_type(2))) _Float16;
using fp16v2 = __attribute__((ext_vector_type(2))) __fp16;   // cvt_pkrtz native

#define LDT 80  // vtrans LDS pad only

__device__ __forceinline__ u16 f2bf(float f) {
  union { float f; unsigned u; } un; un.f = f;
  unsigned r = un.u + 0x7FFFu + ((un.u >> 16) & 1u);  // RNE
  return (u16)(r >> 16);
}
__device__ __forceinline__ float bf2f(u16 b) {
  union { unsigned u; float f; } un; un.u = ((unsigned)b) << 16;
  return un.f;
}

// pack two f32 -> two f16 (RTZ) as _Float16 vector
__device__ __forceinline__ f16x2 pk16(float a, float b) {
  union { fp16v2 v; f16x2 f; } u;
  u.v = __builtin_amdgcn_cvt_pkrtz(a, b);
  return u.f;
}

// async 16B/lane global -> LDS (lands at ldsbase + lane*16)
__device__ __forceinline__ void glds16(const void* g, void* l) {
  __builtin_amdgcn_global_load_lds(
      (__attribute__((address_space(1))) void*)(g),
      (__attribute__((address_space(3))) void*)(l), 16, 0, 0);
}

// ---------------- fp32 -> bf16 cast (vectorized x4) ------------------------
__global__ __launch_bounds__(256) void f2bf_kernel(
    const float* __restrict__ src, u16* __restrict__ dst, int n4)
{
  int i = blockIdx.x * 256 + threadIdx.x;
  if (i < n4) {
    float4 v = ((const float4*)src)[i];
    ushort4 o;
    o.x = f2bf(v.x); o.y = f2bf(v.y); o.z = f2bf(v.z); o.w = f2bf(v.w);
    ((ushort4*)dst)[i] = o;
  }
}

// ------- RoPE table: RT[m][lr] = {cos[m][lr+16j]}{sin[m][lr+16j]} bf16 -----
__global__ __launch_bounds__(256) void rope_table_kernel(
    const float* __restrict__ cs, const float* __restrict__ sn,
    u16* __restrict__ RT)
{
  int t = blockIdx.x * 256 + threadIdx.x;   // 8192*16 = 131072 exact
  int lr = t & 15, m = t >> 4;
  const float* c = cs + (size_t)m * 64;
  const float* s = sn + (size_t)m * 64;
  alignas(16) u16 o[8];
  o[0] = f2bf(c[lr]); o[1] = f2bf(c[lr + 16]);
  o[2] = f2bf(c[lr + 32]); o[3] = f2bf(c[lr + 48]);
  o[4] = f2bf(s[lr]); o[5] = f2bf(s[lr + 16]);
  o[6] = f2bf(s[lr + 32]); o[7] = f2bf(s[lr + 48]);
  *(uint4*)(RT + (size_t)t * 8) = *(const uint4*)o;
}

// ------ 128x128 BT-GEMM core, glds staging + XOR bank swizzle --------------
__device__ __forceinline__ void gemm_core_128(
    const u16* __restrict__ A, const u16* __restrict__ Bm, int K,
    int row0, int col0, u16* As, u16* Bs, f32x4 acc[4][4])
{
  const int tid = threadIdx.x;
  const int lane = tid & 63;
  const int w  = tid >> 6;
  const int wm = (w >> 1) << 6;
  const int wn = (w & 1) << 6;
  const int lr = lane & 15;
  const int lq = lane >> 4;
  const int lrow = lane >> 3;
  const int lcol8 = lane & 7;

  for (int k0 = 0; k0 < K; k0 += 64) {
    __syncthreads();
#pragma unroll
    for (int p = 0; p < 4; ++p) {
      int base = w * 32 + p * 8;
      int rr = base + lrow;
      int cc = (lcol8 ^ (rr & 7)) << 3;
      glds16(A  + (size_t)(row0 + rr) * K + k0 + cc, &As[base * 64]);
      glds16(Bm + (size_t)(col0 + rr) * K + k0 + cc, &Bs[base * 64]);
    }
    __syncthreads();
#pragma unroll
    for (int kx = 0; kx < 2; ++kx) {
      bf16x8 af[4], bv[4];
      const int sl = (((kx << 2) + lq) ^ (lr & 7)) << 3;
#pragma unroll
      for (int i = 0; i < 4; ++i) {
        af[i] = *(const bf16x8*)(&As[(wm + i * 16 + lr) * 64 + sl]);
        bv[i] = *(const bf16x8*)(&Bs[(wn + i * 16 + lr) * 64 + sl]);
      }
#pragma unroll
      for (int i = 0; i < 4; ++i)
#pragma unroll
        for (int j = 0; j < 4; ++j)
          acc[i][j] = __builtin_amdgcn_mfma_f32_16x16x32_bf16(af[i], bv[j], acc[i][j], 0, 0, 0);
    }
  }
}

// ------- QKV projection + bias + fused RoPE (table) + scale ----------------
__global__ __launch_bounds__(256) void qkv_gemm_kernel(
    const u16* __restrict__ hs, const u16* __restrict__ wq,
    const float* __restrict__ bias, const u16* __restrict__ RT,
    u16* __restrict__ Q, u16* __restrict__ K, u16* __restrict__ V)
{
  __shared__ __align__(16) u16 As[128 * 64];
  __shared__ __align__(16) u16 Bs[128 * 64];
  f32x4 acc[4][4];
#pragma unroll
  for (int i = 0; i < 4; ++i)
#pragma unroll
    for (int j = 0; j < 4; ++j) acc[i][j] = (f32x4){0.f, 0.f, 0.f, 0.f};

  const int row0 = blockIdx.y * 128;   // m = b*2048 + s
  const int col0 = blockIdx.x * 128;   // n in [0,3072)
  gemm_core_128(hs, wq, 1024, row0, col0, As, Bs, acc);

  const int lane = threadIdx.x & 63;
  const int w = threadIdx.x >> 6;
  const int lr = lane & 15, lq = lane >> 4;
  const int wm = (w >> 1) << 6, wn = (w & 1) << 6;
  const int ncol = col0 + wn;          // 64-aligned -> single (wh,h)
  const int wh = ncol >> 10;           // 0=q 1=k 2=v (wave-uniform)
  const int h  = (ncol & 1023) >> 6;
  u16* dst = (wh == 0) ? Q : ((wh == 1) ? K : V);
  const float b0 = bias[ncol + lr];
  const float b1 = bias[ncol + 16 + lr];
  const float b2 = bias[ncol + 32 + lr];
  const float b3 = bias[ncol + 48 + lr];

#pragma unroll
  for (int i = 0; i < 4; ++i)
#pragma unroll
    for (int r = 0; r < 4; ++r) {
      int m = row0 + wm + i * 16 + lq * 4 + r;   // = b*2048 + s
      float v0 = acc[i][0][r] + b0;
      float v1 = acc[i][1][r] + b1;
      float v2 = acc[i][2][r] + b2;
      float v3 = acc[i][3][r] + b3;
      int b = m >> 11, s = m & 2047;
      size_t off = ((size_t)((b << 4) + h) * 2048 + s) * 64;
      if (wh == 2) {                   // V -> f16
        union { _Float16 h2; u16 u; } c0, c1, c2, c3;
        c0.h2 = (_Float16)v0; c1.h2 = (_Float16)v1;
        c2.h2 = (_Float16)v2; c3.h2 = (_Float16)v3;
        dst[off + lr]      = c0.u;
        dst[off + 16 + lr] = c1.u;
        dst[off + 32 + lr] = c2.u;
        dst[off + 48 + lr] = c3.u;
      } else {                         // RoPE via table; Q gets 1/8*log2(e)
        alignas(16) u16 rv[8];
        *(uint4*)rv = *(const uint4*)(RT + ((size_t)m * 16 + lr) * 8);
        float o0 = v0 * bf2f(rv[0]) - v2 * bf2f(rv[4]);
        float o1 = v1 * bf2f(rv[1]) - v3 * bf2f(rv[5]);
        float o2 = v2 * bf2f(rv[2]) + v0 * bf2f(rv[6]);
        float o3 = v3 * bf2f(rv[3]) + v1 * bf2f(rv[7]);
        float sc8 = (wh == 0) ? 0.1803368801f : 1.0f;
        dst[off + lr]      = f2bf(o0 * sc8);
        dst[off + 16 + lr] = f2bf(o1 * sc8);
        dst[off + 32 + lr] = f2bf(o2 * sc8);
        dst[off + 48 + lr] = f2bf(o3 * sc8);
      }
    }
}

// ---------------- V [B,H,S,D] -> Vt [B,H,D,S] (bit-moves) ------------------
__global__ __launch_bounds__(256) void vtrans_kernel(
    const u16* __restrict__ V, u16* __restrict__ Vt)
{
  __shared__ __align__(16) u16 T[64][LDT];
  const int bh = blockIdx.y;
  const int s0 = blockIdx.x * 64;
  const u16* src = V + ((size_t)bh * 2048 + s0) * 64;
  const int r = threadIdx.x >> 2;
  const int c = (threadIdx.x & 3) << 4;
  *(uint4*)(&T[r][c])     = *(const uint4*)(src + r * 64 + c);
  *(uint4*)(&T[r][c + 8]) = *(const uint4*)(src + r * 64 + c + 8);
  __syncthreads();
  alignas(16) u16 tmp[16];
#pragma unroll
  for (int j = 0; j < 16; ++j) tmp[j] = T[c + j][r];
  u16* dst = Vt + ((size_t)bh * 64 + r) * 2048 + s0 + c;
  *(uint4*)(dst)     = *(uint4*)(&tmp[0]);
  *(uint4*)(dst + 8) = *(uint4*)(&tmp[8]);
}

// ---- attention: S^T trick, double-buffered staging, 1 barrier/iter --------
__device__ __forceinline__ void attn_stage(
    const u16* __restrict__ Kh, const u16* __restrict__ Vh, int kv0,
    u16* KsB, u16* VsB, int w, int lrow, int lcol8)
{
#pragma unroll
  for (int p = 0; p < 2; ++p) {
    int base = w * 16 + p * 8;
    int rr = base + lrow;
    int cc = (lcol8 ^ (rr & 7)) << 3;
    glds16(Kh + (size_t)(kv0 + rr) * 64 + cc, KsB + base * 64);
    glds16(Vh + (size_t)rr * 2048 + kv0 + cc, VsB + base * 64);
  }
}

__global__ __launch_bounds__(256, 4) void attn_kernel(
    const u16* __restrict__ Q, const u16* __restrict__ K,
    const u16* __restrict__ Vt, u16* __restrict__ O)
{
  __shared__ __align__(16) u16 Ks[2][64 * 64];
  __shared__ __align__(16) u16 Vs[2][64 * 64];
  const int bh = blockIdx.y;
  const int q0 = blockIdx.x << 7;
  const int b = bh >> 4, h = bh & 15;
  const u16* Qh = Q  + (size_t)bh * (2048 * 64);
  const u16* Kh = K  + (size_t)bh * (2048 * 64);
  const u16* Vh = Vt + (size_t)bh * (64 * 2048);
  const int tid = threadIdx.x, lane = tid & 63, w = tid >> 6;
  const int lr = lane & 15, lq = lane >> 4;
  const int lrow = lane >> 3, lcol8 = lane & 7;
  const int wq0 = w * 32;

  // prefetch tile 0
  attn_stage(Kh, Vh, 0, Ks[0], Vs[0], w, lrow, lcol8);

  // Q fragments: iter-invariant, straight from global (B-operand, n=q)
  bf16x8 qa[2][2];
#pragma unroll
  for (int mi = 0; mi < 2; ++mi)
#pragma unroll
    for (int kx = 0; kx < 2; ++kx)
      qa[mi][kx] = *(const bf16x8*)(Qh + (size_t)(q0 + wq0 + mi * 16 + lr) * 64 + kx * 32 + lq * 8);

  f32x4 acc_o[2][4];
  float lsum[2] = {0.f, 0.f};
#pragma unroll
  for (int mi = 0; mi < 2; ++mi)
#pragma unroll
    for (int td = 0; td < 4; ++td) acc_o[mi][td] = (f32x4){0.f, 0.f, 0.f, 0.f};

  for (int it = 0; it < 32; ++it) {
    const int cur = it & 1;
    __syncthreads();                       // drains staging of buf(cur)
    if (it + 1 < 32)                       // prefetch next into other buffer
      attn_stage(Kh, Vh, (it + 1) << 6, Ks[cur ^ 1], Vs[cur ^ 1], w, lrow, lcol8);
    const u16* Kc = Ks[cur];
    const u16* Vc = Vs[cur];

    // S^T = K Q^T : tiles [kv=tj*16][q=mi*16], contraction over d
    f32x4 st[4][2];
#pragma unroll
    for (int tj = 0; tj < 4; ++tj)
#pragma unroll
      for (int mi = 0; mi < 2; ++mi) st[tj][mi] = (f32x4){0.f, 0.f, 0.f, 0.f};
#pragma unroll
    for (int kx = 0; kx < 2; ++kx) {
      bf16x8 ka[4];
#pragma unroll
      for (int tj = 0; tj < 4; ++tj) {
        int row = tj * 16 + lr;
        ka[tj] = *(const bf16x8*)(&Kc[row * 64 + ((((kx << 2) + lq) ^ (lr & 7)) << 3)]);
      }
#pragma unroll
      for (int tj = 0; tj < 4; ++tj)
#pragma unroll
        for (int mi = 0; mi < 2; ++mi)
          st[tj][mi] = __builtin_amdgcn_mfma_f32_16x16x32_bf16(ka[tj], qa[mi][kx], st[tj][mi], 0, 0, 0);
    }

    // p = 2^s (log2e pre-folded into Q); pack straight into PV A-frags
    f16x4 pa[2][4];
#pragma unroll
    for (int mi = 0; mi < 2; ++mi)
#pragma unroll
      for (int tj = 0; tj < 4; ++tj) {
        float e0 = __builtin_amdgcn_exp2f(st[tj][mi][0]);
        float e1 = __builtin_amdgcn_exp2f(st[tj][mi][1]);
        float e2 = __builtin_amdgcn_exp2f(st[tj][mi][2]);
        float e3 = __builtin_amdgcn_exp2f(st[tj][mi][3]);
        lsum[mi] += (e0 + e1) + (e2 + e3);
        f16x2 lo = pk16(e0, e1);
        f16x2 hi = pk16(e2, e3);
        f16x4 p4;
        p4[0] = lo[0]; p4[1] = lo[1]; p4[2] = hi[0]; p4[3] = hi[1];
        pa[mi][tj] = p4;
      }

    // O += P V  (K=16 f16 MFMA; A-frag == S^T C-layout, identity)
#pragma unroll
    for (int t16 = 0; t16 < 4; ++t16) {
      f16x4 bv[4];
#pragma unroll
      for (int td = 0; td < 4; ++td) {
        int row = td * 16 + lr;
        int qc = (t16 << 1) + (lq >> 1);
        bv[td] = *(const f16x4*)(&Vc[row * 64 + ((qc ^ (lr & 7)) << 3) + ((lq & 1) << 2)]);
      }
#pragma unroll
      for (int td = 0; td < 4; ++td)
#pragma unroll
        for (int mi = 0; mi < 2; ++mi)
          acc_o[mi][td] = __builtin_amdgcn_mfma_f32_16x16x16f16(pa[mi][t16], bv[td], acc_o[mi][td], 0, 0, 0);
    }
  }

  // lsum lives at q=lr: reduce over the 4 quads, then fetch per-(lq,r) value
#pragma unroll
  for (int mi = 0; mi < 2; ++mi) {
    lsum[mi] += __shfl_xor(lsum[mi], 16, 64);
    lsum[mi] += __shfl_xor(lsum[mi], 32, 64);
  }
#pragma unroll
  for (int mi = 0; mi < 2; ++mi)
#pragma unroll
    for (int r = 0; r < 4; ++r) {
      float inv = 1.f / __shfl(lsum[mi], lq * 4 + r, 64);
      int qq = q0 + wq0 + mi * 16 + lq * 4 + r;
#pragma unroll
      for (int td = 0; td < 4; ++td) {
        int d = td * 16 + lr;
        O[(size_t)(b * 2048 + qq) * 1024 + h * 64 + d] = f2bf(acc_o[mi][td][r] * inv);
      }
    }
}

// ---------------- output projection (fp32 out) -----------------------------
__global__ __launch_bounds__(256) void proj_gemm_kernel(
    const u16* __restrict__ X, const u16* __restrict__ wp,
    const float* __restrict__ bias, float* __restrict__ out)
{
  __shared__ __align__(16) u16 As[128 * 64];
  __shared__ __align__(16) u16 Bs[128 * 64];
  f32x4 acc[4][4];
#pragma unroll
  for (int i = 0; i < 4; ++i)
#pragma unroll
    for (int j = 0; j < 4; ++j) acc[i][j] = (f32x4){0.f, 0.f, 0.f, 0.f};

  const int row0 = blockIdx.y * 128;
  const int col0 = blockIdx.x * 128;
  gemm_core_128(X, wp, 1024, row0, col0, As, Bs, acc);

  const int lane = threadIdx.x & 63;
  const int w = threadIdx.x >> 6;
  const int wm = (w >> 1) << 6, wn = (w & 1) << 6;
#pragma unroll
  for (int i = 0; i < 4; ++i)
#pragma unroll
    for (int j = 0; j < 4; ++j)
#pragma unroll
      for (int r = 0; r < 4; ++r) {
        int m = row0 + wm + i * 16 + ((lane >> 4) << 2) + r;
        int n = col0 + wn + j * 16 + (lane & 15);
        out[(size_t)m * 1024 + n] = acc[i][j][r] + bias[n];
      }
}

extern "C" void kernel_launch(void* const* d_in, const int* in_sizes, int n_in,
                              void* d_out, int out_size, void* d_ws, size_t ws_size,
                              hipStream_t stream)
{
  const float* hs   = (const float*)d_in[0];
  const float* cs   = (const float*)d_in[1];
  const float* sn   = (const float*)d_in[2];
  const float* qkvw = (const float*)d_in[3];
  const float* qkvb = (const float*)d_in[4];
  const float* pw   = (const float*)d_in[5];
  const float* pb   = (const float*)d_in[6];
  float* out = (float*)d_out;

  const size_t NQ = (size_t)8192 * 1024;
  u16* hsb   = (u16*)d_ws;
  u16* qkvwb = hsb + NQ;
  u16* pwb   = qkvwb + 3145728;
  u16* Qb    = pwb + 1048576;
  u16* Kb    = Qb + NQ;
  u16* Vb    = Kb + NQ;      // f16
  u16* Vtb   = Vb + NQ;      // f16
  u16* RT    = Vtb + NQ;     // rope table, 8192*16*8 u16 = 2 MB
  u16* Ob    = hsb;          // alias: hs consumed after qkv

  f2bf_kernel<<<8192, 256, 0, stream>>>(hs, hsb, (int)(NQ / 4));
  f2bf_kernel<<<3072, 256, 0, stream>>>(qkvw, qkvwb, 3145728 / 4);
  f2bf_kernel<<<1024, 256, 0, stream>>>(pw, pwb, 1048576 / 4);
  rope_table_kernel<<<512, 256, 0, stream>>>(cs, sn, RT);

  qkv_gemm_kernel<<<dim3(24, 64), 256, 0, stream>>>(hsb, qkvwb, qkvb, RT, Qb, Kb, Vb);
  vtrans_kernel<<<dim3(32, 64), 256, 0, stream>>>(Vb, Vtb);
  attn_kernel<<<dim3(16, 64), 256, 0, stream>>>(Qb, Kb, Vtb, Ob);
  proj_gemm_kernel<<<dim3(8, 64), 256, 0, stream>>>(Ob, pwb, pb, out);
}